// Round 4
// baseline (501.998 us; speedup 1.0000x reference)
//
#include <hip/hip_runtime.h>
#include <hip/hip_bf16.h>
#include <math.h>

// ---------------------------------------------------------------------------
// TransformerDecoderBlock  (B=4, S=2048, E=768, DFF=3072)
// Round 10: address-path cleanup on the 8-phase core:
//  (1) 8 precomputed LDS read-base registers (A/B x buf0/buf1 x s0/s1) so all
//      ds_read_b128 are base+imm (buf1 byte offset 65536 > 16-bit imm forced
//      per-read v_add before).
//  (2) staging global pointers hoisted (top/bot halves precomputed; per-stg
//      address = base + uniform t*64).
//  (3) m201's pre-barrier s_waitcnt lgkmcnt(8) on the 12-read phases (P1/P5).
//  (4) ln1 residual base reads bf16 xb (was f32 x): halves ln1 input traffic.
//  (5) lsum zeroing folded into cvt_all (memset dispatch removed).
// Core otherwise: 256x256 8-phase, BK=64, T2 swizzle, T5 setprio, 8 barriers
// per iter, earliest-legal staging with vmcnt(6) (never 0 in loop).
// ---------------------------------------------------------------------------

typedef __bf16 bf16_t;
typedef bf16_t bf16x4 __attribute__((ext_vector_type(4)));
typedef bf16_t bf16x8 __attribute__((ext_vector_type(8)));
typedef float f32x4 __attribute__((ext_vector_type(4)));

struct MMDesc {
    const bf16_t* A;
    const bf16_t* B;
    const float* bias;
    __hip_bfloat16* C;
    float* lsum;
    int koff;
    int trans;  // epilogue writes C transposed into [E][2048-per-batch] layout
};
struct MMArgs { MMDesc g[8]; };

// bijective XCD swizzle (m204): contiguous chunk per XCD, any grid size
__device__ __forceinline__ int xcd_swz(int bid, int nwg) {
    const int q = nwg >> 3, r = nwg & 7;
    const int xcd = bid & 7, o = bid >> 3;
    const int base = (xcd < r) ? xcd * (q + 1) : r * (q + 1) + (xcd - r) * q;
    return base + o;
}

// async global->LDS, 16B per lane. LDS dest = wave-uniform base + lane*16.
__device__ __forceinline__ void load16(const bf16_t* g, bf16_t* l) {
    __builtin_amdgcn_global_load_lds(
        (const __attribute__((address_space(1))) unsigned int*)g,
        (__attribute__((address_space(3))) unsigned int*)l, 16, 0, 0);
}

// ---- 8-phase core helpers ----
// p0/p1: s0/s1 base pointers (buf + operand resolved); H: half offset (imm).
__device__ __forceinline__ void rd4h(const bf16_t* p0, const bf16_t* p1, int H,
                                     bf16x8 f[4][2]) {
#pragma unroll
    for (int i = 0; i < 4; ++i) {
        f[i][0] = *(const bf16x8*)(p0 + H + i * 1024);
        f[i][1] = *(const bf16x8*)(p1 + H + i * 1024);
    }
}
__device__ __forceinline__ void rd2h(const bf16_t* p0, const bf16_t* p1, int H,
                                     bf16x8 f[2][2]) {
#pragma unroll
    for (int i = 0; i < 2; ++i) {
        f[i][0] = *(const bf16x8*)(p0 + H + i * 1024);
        f[i][1] = *(const bf16x8*)(p1 + H + i * 1024);
    }
}

#define SBAR asm volatile("s_barrier" ::: "memory")
#define SCH  __builtin_amdgcn_sched_barrier(0)
#define PBAR do { SCH; SBAR; SCH; } while (0)
#define PRIO1 __builtin_amdgcn_s_setprio(1)
#define PRIO0 __builtin_amdgcn_s_setprio(0)
#define VMC6 asm volatile("s_waitcnt vmcnt(6)" ::: "memory")
#define LGK8 do { asm volatile("s_waitcnt lgkmcnt(8)" ::: "memory"); } while (0)

#define QMFMA(mh, nh, BF) do { \
    _Pragma("unroll") \
    for (int ks = 0; ks < 2; ++ks) \
    _Pragma("unroll") \
    for (int mi = 0; mi < 4; ++mi) \
    _Pragma("unroll") \
    for (int ni = 0; ni < 2; ++ni) \
        acc[(mh) * 4 + mi][(nh) * 2 + ni] = __builtin_amdgcn_mfma_f32_16x16x32_bf16( \
            af[mi][ks], BF[ni][ks], acc[(mh) * 4 + mi][(nh) * 2 + ni], 0, 0, 0); \
} while (0)

// 256x256 tile, BK=64, 8 waves. LDS layout (elems): [buf:32768][op:16384]
// [half:8192][row:64] with 16B slot swizzle slot^= (row&7). K multiple of 128.
// Staging schedule (earliest-legal): P1 Ab(t1); P3 At,Bt(t2); P4 Bb(t2)+VMC6
// (certifies buf1(t1)); P5 Ab(t2); P7 At,Bt(t3); P8 Bb(t3)+VMC6 (certifies
// buf0(t2)). Prologue 7 halftiles, VMC6 certifies buf0(t0).
__device__ __forceinline__ void mm8_core(
    const bf16_t* Ag, const bf16_t* Bg, int lda, int ldb, int K,
    bf16_t* lds, int w, int l, f32x4 acc[8][4])
{
    const long ldal = lda, ldbl = ldb;
    const int fr = l & 15, kq = l >> 4;
    // staging geometry: lane l -> row rr, 16B slot (l&7), logical slot c8=(l&7)^(rr&7)
    const int rr = w * 8 + (l >> 3);
    const int c8e = ((l & 7) ^ (l >> 3)) * 8;
    // hoisted global staging bases: [op][half]
    const bf16_t* pA[2];
    const bf16_t* pB[2];
    pA[0] = Ag + (long)rr * ldal + c8e;
    pA[1] = pA[0] + 128 * ldal;
    pB[0] = Bg + (long)rr * ldbl + c8e;
    pB[1] = pB[0] + 128 * ldbl;
    // ds_read swizzled slot offsets for k-sub 0/1 (row&7 == fr&7, 16|rowbase)
    const int s0 = ((0 + kq) ^ (fr & 7)) * 8;
    const int s1 = ((4 + kq) ^ (fr & 7)) * 8;
    // 8 read-base registers: [buf][s] for A and B; all reads imm off these.
    const int arow = ((w >> 2) * 64 + fr) * 64;
    const int brow = ((w & 3) * 32 + fr) * 64;
    const bf16_t* lA0s0 = lds + arow + s0;
    const bf16_t* lA0s1 = lds + arow + s1;
    const bf16_t* lA1s0 = lds + 32768 + arow + s0;
    const bf16_t* lA1s1 = lds + 32768 + arow + s1;
    const bf16_t* lB0s0 = lds + 16384 + brow + s0;
    const bf16_t* lB0s1 = lds + 16384 + brow + s1;
    const bf16_t* lB1s0 = lds + 49152 + brow + s0;
    const bf16_t* lB1s1 = lds + 49152 + brow + s1;
    bf16_t* stA = lds + w * 512;
    bf16_t* stB = lds + 16384 + w * 512;

    auto stg = [&](int b, int isB, int h, int t) {
        const bf16_t* g = (isB ? pB[h] : pA[h]) + (long)t * 64;
        bf16_t* d = (isB ? stB : stA) + b * 32768 + h * 8192;
        load16(g, d);
        load16(g + 64 * (isB ? ldbl : ldal), d + 4096);
    };

    bf16x8 af[4][2], bf0[2][2], bf1[2][2];
    const int NT = K >> 6, NI = NT >> 1;

    // prologue: At0 Bt0 Bb0 Ab0 At1 Bt1 Bb1 (7 halftiles, 14 loads);
    // vmcnt(6) completes the oldest 8 = all of buf0(t0).
    stg(0, 0, 0, 0); stg(0, 1, 0, 0); stg(0, 1, 1, 0); stg(0, 0, 1, 0);
    stg(1, 0, 0, 1); stg(1, 1, 0, 1); stg(1, 1, 1, 1);
    VMC6;
    SBAR; SCH;

    for (int i = 0; i < NI; ++i) {
        const int t1 = 2 * i + 1;
        int t2 = 2 * i + 2; if (t2 >= NT) t2 -= 2;  // tail: clamp, data unused
        int t3 = 2 * i + 3; if (t3 >= NT) t3 -= 2;
        // P1: quad (0,0) of even tile; stage Ab(t1)
        rd4h(lA0s0, lA0s1, 0, af); rd2h(lB0s0, lB0s1, 0, bf0);
        stg(1, 0, 1, t1);
        LGK8;
        PBAR; PRIO1; QMFMA(0, 0, bf0); PRIO0;
        // P2: (0,1); no stage
        rd2h(lB0s0, lB0s1, 8192, bf1);
        PBAR; PRIO1; QMFMA(0, 1, bf1); PRIO0;
        // P3: (1,0); stage At(t2), Bt(t2)
        rd4h(lA0s0, lA0s1, 8192, af);
        stg(0, 0, 0, t2); stg(0, 1, 0, t2);
        PBAR; PRIO1; QMFMA(1, 0, bf0); PRIO0;
        // P4: (1,1); stage Bb(t2); counted drain certifies buf1(t1)
        stg(0, 1, 1, t2);
        VMC6;
        PBAR; PRIO1; QMFMA(1, 1, bf1); PRIO0;
        // P5: (0,0) of odd tile; stage Ab(t2)
        rd4h(lA1s0, lA1s1, 0, af); rd2h(lB1s0, lB1s1, 0, bf0);
        stg(0, 0, 1, t2);
        LGK8;
        PBAR; PRIO1; QMFMA(0, 0, bf0); PRIO0;
        // P6: (0,1); no stage
        rd2h(lB1s0, lB1s1, 8192, bf1);
        PBAR; PRIO1; QMFMA(0, 1, bf1); PRIO0;
        // P7: (1,0); stage At(t3), Bt(t3)
        rd4h(lA1s0, lA1s1, 8192, af);
        stg(1, 0, 0, t3); stg(1, 1, 0, t3);
        PBAR; PRIO1; QMFMA(1, 0, bf0); PRIO0;
        // P8: (1,1); stage Bb(t3); counted drain certifies buf0(t2)
        stg(1, 1, 1, t3);
        VMC6;
        PBAR; PRIO1; QMFMA(1, 1, bf1); PRIO0;
    }
    // all in-flight (garbage tail) staging must land before LDS reuse
    asm volatile("s_waitcnt vmcnt(0)" ::: "memory");
    SBAR; SCH;
}

// Standard GEMM: C[M,N] = scale*A@B^T + bias, opt ReLU, bf16 out.
// CLAMPK: K clamped to (by+1)*256 - koff (causal PV); zero tile if <=0.
// dsc.trans: write transposed into vtb layout [batch][N][2048].
template <bool RELU, bool CLAMPK>
__global__ __launch_bounds__(512, 2) void mm8_std(
    MMArgs args, int M, int N, int K, int lda, int ldb, float scale, int GX)
{
    __shared__ __align__(16) bf16_t lds[65536];  // 128 KiB
    const MMDesc dsc = args.g[blockIdx.z];

    const int lin = xcd_swz(blockIdx.x, gridDim.x);
    const int panel = lin / (8 * GX);
    const int rem = lin - panel * 8 * GX;
    const int bx = rem >> 3;
    const int by = panel * 8 + (rem & 7);
    const int m0 = by * 256, n0 = bx * 256;
    const int tid = threadIdx.x, w = tid >> 6, l = tid & 63;

    f32x4 acc[8][4];
    const f32x4 z4 = {0.f, 0.f, 0.f, 0.f};
#pragma unroll
    for (int i = 0; i < 8; ++i)
#pragma unroll
        for (int j = 0; j < 4; ++j) acc[i][j] = z4;

    int Keff = K;
    if (CLAMPK) {
        int km = (by + 1) * 256 - dsc.koff;
        Keff = km < K ? km : K;
    }
    if (!CLAMPK || Keff > 0)
        mm8_core(dsc.A + (long)m0 * lda, dsc.B + (long)n0 * ldb,
                 lda, ldb, Keff, lds, w, l, acc);

    // epilogue: bias/scale/relu -> LDS stage (two 128-row halves) -> coalesced out
    const int fr = l & 15, erow = (l >> 4) * 4;
    const int wrow = (w >> 2) * 64, wcol = (w & 3) * 32;
    bf16_t* ctb = lds;
    __hip_bfloat16* ct = (__hip_bfloat16*)lds;
#pragma unroll
    for (int mh = 0; mh < 2; ++mh) {
        if (mh) __syncthreads();
#pragma unroll
        for (int nh = 0; nh < 2; ++nh)
#pragma unroll
            for (int ni = 0; ni < 2; ++ni) {
                const int cl = nh * 128 + wcol + ni * 16 + fr;
                const float bv = dsc.bias ? dsc.bias[n0 + cl] : 0.f;
#pragma unroll
                for (int mi = 0; mi < 4; ++mi) {
                    const int lr = wrow + mi * 16 + erow;
                    const f32x4 a = acc[mh * 4 + mi][nh * 2 + ni];
                    if (dsc.trans) {
                        bf16x4 p;
#pragma unroll
                        for (int r = 0; r < 4; ++r) {
                            float v = a[r] * scale + bv;
                            if (RELU) v = fmaxf(v, 0.f);
                            p[r] = (bf16_t)v;
                        }
                        *(bf16x4*)(ctb + cl * 140 + lr) = p;
                    } else {
#pragma unroll
                        for (int r = 0; r < 4; ++r) {
                            float v = a[r] * scale + bv;
                            if (RELU) v = fmaxf(v, 0.f);
                            ct[(lr + r) * 264 + cl] = __float2bfloat16(v);
                        }
                    }
                }
            }
        __syncthreads();
        if (dsc.trans) {  // V projection -> vtb[batch][e][s]
            __hip_bfloat16* base = dsc.C + ((long)(m0 >> 11) * N + n0) * 2048
                                 + (m0 & 2047) + mh * 128;
#pragma unroll
            for (int u = 0; u < 8; ++u) {
                const int e = u * 4096 + tid * 8;
                const int rl = e >> 7, cl = e & 127;
                const bf16_t* src = ctb + rl * 140 + cl;
                const uint2 lo = *(const uint2*)(src);
                const uint2 hi = *(const uint2*)(src + 4);
                const uint4 v = {lo.x, lo.y, hi.x, hi.y};
                *(uint4*)(base + (long)rl * 2048 + cl) = v;
            }
        } else {
            __hip_bfloat16* base = dsc.C + (long)(m0 + mh * 128) * N + n0;
#pragma unroll
            for (int u = 0; u < 8; ++u) {
                const int e = u * 4096 + tid * 8;
                *(uint4*)(base + (long)(e >> 8) * N + (e & 255))
                    = *(const uint4*)(ct + (e >> 8) * 264 + (e & 255));
            }
        }
    }
}

// QK^T with fused exp epilogue: P~ = exp(scale*(A@B^T)) bf16, row sums -> lsum.
template <bool CAUSAL>
__global__ __launch_bounds__(512, 2) void mm8_exp(
    MMArgs args, int N, int K, int lda, int ldb, float scale, int GX)
{
    __shared__ __align__(16) bf16_t lds[65536];
    const MMDesc dsc = args.g[blockIdx.z];

    int bx, by;
    if (CAUSAL) {
        const int t = xcd_swz(blockIdx.x, gridDim.x);
        by = (int)((sqrtf(8.f * t + 1.f) - 1.f) * 0.5f);
        while ((by + 1) * (by + 2) / 2 <= t) ++by;
        while (by * (by + 1) / 2 > t) --by;
        bx = t - by * (by + 1) / 2;
    } else {
        const int lin = xcd_swz(blockIdx.x, gridDim.x);
        const int panel = lin / (8 * GX);
        const int rem = lin - panel * 8 * GX;
        bx = rem >> 3;
        by = panel * 8 + (rem & 7);
    }
    const int m0 = by * 256, n0 = bx * 256;
    const int tid = threadIdx.x, w = tid >> 6, l = tid & 63;

    f32x4 acc[8][4];
    const f32x4 z4 = {0.f, 0.f, 0.f, 0.f};
#pragma unroll
    for (int i = 0; i < 8; ++i)
#pragma unroll
        for (int j = 0; j < 4; ++j) acc[i][j] = z4;

    mm8_core(dsc.A + (long)m0 * lda, dsc.B + (long)n0 * ldb,
             lda, ldb, K, lds, w, l, acc);

    const int fr = l & 15, erow = (l >> 4) * 4;
    const int wrow = (w >> 2) * 64, wcol = (w & 3) * 32;
    __hip_bfloat16* ct = (__hip_bfloat16*)lds;
#pragma unroll
    for (int mh = 0; mh < 2; ++mh) {
        if (mh) __syncthreads();
#pragma unroll
        for (int mi = 0; mi < 4; ++mi) {
            const int lr = wrow + mi * 16 + erow;
#pragma unroll
            for (int r = 0; r < 4; ++r) {
                const int grow = m0 + mh * 128 + lr + r;
                float rs = 0.f;
#pragma unroll
                for (int nh = 0; nh < 2; ++nh)
#pragma unroll
                    for (int ni = 0; ni < 2; ++ni) {
                        const int cl = nh * 128 + wcol + ni * 16 + fr;
                        float e;
                        if (CAUSAL && (n0 + cl) > grow)
                            e = 0.f;
                        else
                            e = __expf(acc[mh * 4 + mi][nh * 2 + ni][r] * scale);
                        ct[(lr + r) * 264 + cl] = __float2bfloat16(e);
                        rs += e;
                    }
#pragma unroll
                for (int o = 8; o > 0; o >>= 1) rs += __shfl_down(rs, o, 16);
                if ((l & 15) == 0) atomicAdd(&dsc.lsum[grow], rs);
            }
        }
        __syncthreads();
        __hip_bfloat16* base = dsc.C + (long)(m0 + mh * 128) * N + n0;
#pragma unroll
        for (int u = 0; u < 8; ++u) {
            const int e = u * 4096 + tid * 8;
            *(uint4*)(base + (long)(e >> 8) * N + (e & 255))
                = *(const uint4*)(ct + (e >> 8) * 264 + (e & 255));
        }
    }
}

// ---------------- reductions ----------------
__device__ __forceinline__ float waveReduceSum(float v) {
#pragma unroll
    for (int o = 32; o > 0; o >>= 1) v += __shfl_down(v, o, 64);
    return v;
}
__device__ __forceinline__ float blockReduceSum(float v, float* s) {
    int lane = threadIdx.x & 63, w = threadIdx.x >> 6;
    v = waveReduceSum(v);
    __syncthreads();
    if (lane == 0) s[w] = v;
    __syncthreads();
    return s[0] + s[1] + s[2] + s[3];
}

// out = LayerNorm(xbase + t) * g + beta.  h1,h2 bf16 partials.
template <bool BR, bool XF32>
__global__ __launch_bounds__(256) void ln_kernel(
    const float* __restrict__ xf, const __hip_bfloat16* __restrict__ xh,
    const __hip_bfloat16* __restrict__ h1, const __hip_bfloat16* __restrict__ h2,
    const float* __restrict__ hbias, const float* __restrict__ lsum,
    const float* __restrict__ g, const float* __restrict__ beta,
    float* __restrict__ outf, __hip_bfloat16* __restrict__ outb) {
    __shared__ float red[4];
    const int E = 768;
    const long row = blockIdx.x;
    const float hscale = lsum ? (1.f / lsum[row]) : 1.f;

    float vals[3];
    float sum = 0.f;
#pragma unroll
    for (int i = 0; i < 3; ++i) {
        int c = threadIdx.x + i * 256;
        float t = __bfloat162float(h1[row * E + c]) + __bfloat162float(h2[row * E + c]);
        if (BR) t = fmaxf(t + hbias[c], 0.f);
        else t *= hscale;
        float xv = XF32 ? xf[row * E + c] : __bfloat162float(xh[row * E + c]);
        vals[i] = xv + t;
        sum += vals[i];
    }
    sum = blockReduceSum(sum, red);
    const float mean = sum * (1.f / 768.f);

    float ss = 0.f;
#pragma unroll
    for (int i = 0; i < 3; ++i) {
        float d = vals[i] - mean;
        ss += d * d;
    }
    ss = blockReduceSum(ss, red);
    const float inv = rsqrtf(ss * (1.f / 768.f) + 1e-5f);

#pragma unroll
    for (int i = 0; i < 3; ++i) {
        int c = threadIdx.x + i * 256;
        float v = (vals[i] - mean) * inv * g[c] + beta[c];
        if (outf) outf[row * E + c] = v;
        if (outb) outb[row * E + c] = __float2bfloat16(v);
    }
}

// one launch converts all fp32->bf16 (8 weights + x + kv) and zeroes lsum.
struct CvtPtrs {
    const float* s[10];
    __hip_bfloat16* d[10];
    float* zero;  // 2*Nr floats to zero
};
__global__ __launch_bounds__(256) void cvt_all(CvtPtrs p) {
    int bid = blockIdx.x, seg, off;
    if (bid >= 20352) {  // zero lsum1+lsum2: 16 blocks x 256 x 4 floats
        int i = (bid - 20352) * 1024 + threadIdx.x * 4;
        float4 z = {0.f, 0.f, 0.f, 0.f};
        *(float4*)(p.zero + i) = z;
        return;
    }
    if (bid < 3456) {
        seg = bid / 576;
        off = (bid % 576) * 1024;
    } else if (bid < 8064) {
        int t = bid - 3456;
        seg = 6 + t / 2304;
        off = (t % 2304) * 1024;
    } else {
        int t = bid - 8064;
        seg = 8 + t / 6144;
        off = (t % 6144) * 1024;
    }
    const float* s = p.s[seg];
    __hip_bfloat16* d = p.d[seg];
    int i = off + threadIdx.x * 4;
    float4 v = *(const float4*)(s + i);
    d[i + 0] = __float2bfloat16(v.x);
    d[i + 1] = __float2bfloat16(v.y);
    d[i + 2] = __float2bfloat16(v.z);
    d[i + 3] = __float2bfloat16(v.w);
}

extern "C" void kernel_launch(void* const* d_in, const int* in_sizes, int n_in,
                              void* d_out, int out_size, void* d_ws, size_t ws_size,
                              hipStream_t stream) {
    const int Bb = 4, S = 2048, E = 768, DFF = 3072;
    const int Nr = Bb * S;  // 8192

    const float* x    = (const float*)d_in[0];
    const float* kv   = (const float*)d_in[1];
    const float* wq_w = (const float*)d_in[2];
    const float* wq_b = (const float*)d_in[3];
    const float* wk_w = (const float*)d_in[4];
    const float* wk_b = (const float*)d_in[5];
    const float* wv_w = (const float*)d_in[6];
    const float* wv_b = (const float*)d_in[7];
    const float* ln1g = (const float*)d_in[8];
    const float* ln1b = (const float*)d_in[9];
    const float* wq2w = (const float*)d_in[10];
    const float* wq2b = (const float*)d_in[11];
    const float* wk2w = (const float*)d_in[12];
    const float* wk2b = (const float*)d_in[13];
    const float* wv2w = (const float*)d_in[14];
    const float* wv2b = (const float*)d_in[15];
    const float* ln2g = (const float*)d_in[16];
    const float* ln2b = (const float*)d_in[17];
    const float* w1   = (const float*)d_in[18];
    const float* b1   = (const float*)d_in[19];
    const float* w2   = (const float*)d_in[20];
    const float* b2   = (const float*)d_in[21];
    const float* ln3g = (const float*)d_in[22];
    const float* ln3b = (const float*)d_in[23];
    float* out = (float*)d_out;

    // ---- workspace (bump allocator, 256B aligned) ~155 MB ----
    char* wsp = (char*)d_ws;
    auto alloc = [&](size_t bytes) {
        char* p = wsp;
        wsp += (bytes + 255) & ~(size_t)255;
        return p;
    };
    const size_t nSE = (size_t)Nr * E;       // 6,291,456
    const size_t nSS = (size_t)Bb * S * S;   // 16,777,216
    __hip_bfloat16* Pb   = (__hip_bfloat16*)alloc(nSS * 2);   // 33.5 MB
    __hip_bfloat16* qb   = (__hip_bfloat16*)alloc(nSE * 2);
    __hip_bfloat16* kb   = (__hip_bfloat16*)alloc(nSE * 2);
    __hip_bfloat16* hffb = Pb;  // MLP hidden overlays Pb+qb+kb (58.7 >= 50.3 MB)
    __hip_bfloat16* vtb  = (__hip_bfloat16*)alloc(nSE * 2);   // V^T [b][E][S]
    __hip_bfloat16* xb   = (__hip_bfloat16*)alloc(nSE * 2);
    __hip_bfloat16* kvb  = (__hip_bfloat16*)alloc(nSE * 2);
    __hip_bfloat16* actb = (__hip_bfloat16*)alloc(nSE * 2);   // residual chain
    __hip_bfloat16* hA   = (__hip_bfloat16*)alloc(nSE * 2);   // split-K partial A
    __hip_bfloat16* hB   = (__hip_bfloat16*)alloc(nSE * 2);   // split-K partial B
    __hip_bfloat16* wqb   = (__hip_bfloat16*)alloc((size_t)E * E * 2);
    __hip_bfloat16* wkb   = (__hip_bfloat16*)alloc((size_t)E * E * 2);
    __hip_bfloat16* wvb   = (__hip_bfloat16*)alloc((size_t)E * E * 2);
    __hip_bfloat16* wq2bm = (__hip_bfloat16*)alloc((size_t)E * E * 2);
    __hip_bfloat16* wk2bm = (__hip_bfloat16*)alloc((size_t)E * E * 2);
    __hip_bfloat16* wv2bm = (__hip_bfloat16*)alloc((size_t)E * E * 2);
    __hip_bfloat16* w1b   = (__hip_bfloat16*)alloc((size_t)DFF * E * 2);
    __hip_bfloat16* w2b   = (__hip_bfloat16*)alloc((size_t)E * DFF * 2);
    float* lsum1 = (float*)alloc((size_t)Nr * 4);
    float* lsum2 = (float*)alloc((size_t)Nr * 4);

    // K2 / V2^T live in d_out used as scratch (exactly 2*nSE*2 bytes = out_size);
    // both are dead before ln3 writes the real output.
    __hip_bfloat16* k2b  = (__hip_bfloat16*)d_out;
    __hip_bfloat16* vtb2 = k2b + nSE;

    const float scale = 1.0f / sqrtf((float)E);
    const dim3 blk(256);
    const dim3 blk5(512);

    // ---- all conversions + lsum zeroing in one launch ----
    CvtPtrs cp;
    cp.s[0] = wq_w; cp.d[0] = wqb;
    cp.s[1] = wk_w; cp.d[1] = wkb;
    cp.s[2] = wv_w; cp.d[2] = wvb;
    cp.s[3] = wq2w; cp.d[3] = wq2bm;
    cp.s[4] = wk2w; cp.d[4] = wk2bm;
    cp.s[5] = wv2w; cp.d[5] = wv2bm;
    cp.s[6] = w1;   cp.d[6] = w1b;
    cp.s[7] = w2;   cp.d[7] = w2b;
    cp.s[8] = x;    cp.d[8] = xb;
    cp.s[9] = kv;   cp.d[9] = kvb;
    cp.zero = lsum1;  // lsum1+lsum2 contiguous (2*Nr floats)
    cvt_all<<<8064 + 12288 + 16, blk, 0, stream>>>(cp);

    // ---- fused projections: Q,K,V(self from xb) + K2,V2(cross from kvb) ----
    {   // 5 z-slices x 96 blocks = 480 blocks
        MMArgs a{};
        a.g[0] = {(const bf16_t*)xb,  (const bf16_t*)wqb,   wq_b, qb,   nullptr, 0, 0};
        a.g[1] = {(const bf16_t*)xb,  (const bf16_t*)wkb,   wk_b, kb,   nullptr, 0, 0};
        a.g[2] = {(const bf16_t*)xb,  (const bf16_t*)wvb,   wv_b, vtb,  nullptr, 0, 1};
        a.g[3] = {(const bf16_t*)kvb, (const bf16_t*)wk2bm, wk2b, k2b,  nullptr, 0, 0};
        a.g[4] = {(const bf16_t*)kvb, (const bf16_t*)wv2bm, wv2b, vtb2, nullptr, 0, 1};
        mm8_std<false, false><<<dim3(96, 1, 5), blk5, 0, stream>>>(
            a, Nr, E, E, E, E, 1.f, 3);
    }
    // ---- causal self-attention ----
    {   // causal QK^T + exp: 36 triangle tiles x 4 batches
        MMArgs a{};
        for (int b = 0; b < 4; ++b)
            a.g[b] = {(const bf16_t*)qb + (long)b * S * E,
                      (const bf16_t*)kb + (long)b * S * E, nullptr,
                      Pb + (long)b * S * S, lsum1 + b * S, 0, 0};
        mm8_exp<true><<<dim3(36, 1, 4), blk5, 0, stream>>>(a, S, E, E, E, scale, 8);
    }
    {   // causal PV split-K=2 with K-clamp, bf16 partials
        MMArgs a{};
        for (int b = 0; b < 4; ++b)
            for (int ks = 0; ks < 2; ++ks)
                a.g[b * 2 + ks] = {(const bf16_t*)Pb + (long)b * S * S + ks * 1024,
                                   (const bf16_t*)vtb + (long)b * E * S + ks * 1024,
                                   nullptr, (ks ? hB : hA) + (long)b * S * E,
                                   nullptr, ks * 1024, 0};
        mm8_std<false, true><<<dim3(24, 1, 8), blk5, 0, stream>>>(
            a, S, E, 1024, S, S, 1.f, 3);
    }
    ln_kernel<false, false><<<Nr, blk, 0, stream>>>(
        nullptr, xb, hA, hB, nullptr, lsum1, ln1g, ln1b, nullptr, actb);

    // ---- cross-attention ----
    {   // Q2 projection only (K2/V2 already done)
        MMArgs a{};
        a.g[0] = {(const bf16_t*)actb, (const bf16_t*)wq2bm, wq2b, qb, nullptr, 0, 0};
        mm8_std<false, false><<<dim3(96, 1, 1), blk5, 0, stream>>>(
            a, Nr, E, E, E, E, 1.f, 3);
    }
    {   // full QK^T + exp: 64 tiles x 4 batches
        MMArgs a{};
        for (int b = 0; b < 4; ++b)
            a.g[b] = {(const bf16_t*)qb + (long)b * S * E,
                      (const bf16_t*)k2b + (long)b * S * E, nullptr,
                      Pb + (long)b * S * S, lsum2 + b * S, 0, 0};
        mm8_exp<false><<<dim3(64, 1, 4), blk5, 0, stream>>>(a, S, E, E, E, scale, 8);
    }
    {   // full PV split-K=2, bf16 partials
        MMArgs a{};
        for (int b = 0; b < 4; ++b)
            for (int ks = 0; ks < 2; ++ks)
                a.g[b * 2 + ks] = {(const bf16_t*)Pb + (long)b * S * S + ks * 1024,
                                   (const bf16_t*)vtb2 + (long)b * E * S + ks * 1024,
                                   nullptr, (ks ? hB : hA) + (long)b * S * E,
                                   nullptr, 0, 0};
        mm8_std<false, false><<<dim3(24, 1, 8), blk5, 0, stream>>>(
            a, S, E, 1024, S, S, 1.f, 3);
    }
    ln_kernel<false, false><<<Nr, blk, 0, stream>>>(
        nullptr, actb, hA, hB, nullptr, lsum2, ln2g, ln2b, nullptr, actb);

    // ---- MLP ----
    {   // MLP1: fused bias+ReLU (hffb overlays Pb/qb/kb)
        MMArgs a{};
        a.g[0] = {(const bf16_t*)actb, (const bf16_t*)w1b, b1, hffb, nullptr, 0, 0};
        mm8_std<true, false><<<dim3(384, 1, 1), blk5, 0, stream>>>(
            a, Nr, DFF, E, E, E, 1.f, 12);
    }
    {   // MLP2 split-K=2, bf16 partials; bias+ReLU applied in ln3
        MMArgs a{};
        a.g[0] = {(const bf16_t*)hffb, (const bf16_t*)w2b, nullptr, hA, nullptr, 0, 0};
        a.g[1] = {(const bf16_t*)hffb + 1536, (const bf16_t*)w2b + 1536, nullptr,
                  hB, nullptr, 0, 0};
        mm8_std<false, false><<<dim3(96, 1, 2), blk5, 0, stream>>>(
            a, Nr, E, 1536, DFF, DFF, 1.f, 3);
    }
    ln_kernel<true, false><<<Nr, blk, 0, stream>>>(
        nullptr, actb, hA, hB, b2, nullptr, ln3g, ln3b, out, nullptr);
}

// Round 5
// 495.882 us; speedup vs baseline: 1.0123x; 1.0123x over previous
//
#include <hip/hip_runtime.h>
#include <hip/hip_bf16.h>
#include <math.h>

// ---------------------------------------------------------------------------
// TransformerDecoderBlock  (B=4, S=2048, E=768, DFF=3072)
// Round 11: software-pipelined phases — one-phase-ahead fragment prefetch.
// Phases re-partitioned by (m-half, k-sub32): each 16-MFMA cluster consumes
// fragments read ONE PHASE EARLIER; each phase prefetches the next phase's
// operands (4-8 ds_read_b128). Fragment liveness = exactly 4 buffers
// (a0,a1,b0,b1 = 64 VGPR, net-zero vs old af/bf0/bf1). Barriers: 2/iter
// (one per K-tile; vmcnt(0) certifies stage loads issued 3-4 phases back).
// Staging: 8 load16 per tile split 4+4 across phi4/phi1 of the prior tiles.
// sched_group_barrier(DS_READ,n)+(MFMA,16) pins the per-phase interleave.
// Epilogues/acc layout/launcher unchanged from R10.
// ---------------------------------------------------------------------------

typedef __bf16 bf16_t;
typedef bf16_t bf16x4 __attribute__((ext_vector_type(4)));
typedef bf16_t bf16x8 __attribute__((ext_vector_type(8)));
typedef float f32x4 __attribute__((ext_vector_type(4)));

struct MMDesc {
    const bf16_t* A;
    const bf16_t* B;
    const float* bias;
    __hip_bfloat16* C;
    float* lsum;
    int koff;
    int trans;  // epilogue writes C transposed into [E][2048-per-batch] layout
};
struct MMArgs { MMDesc g[8]; };

// bijective XCD swizzle (m204): contiguous chunk per XCD, any grid size
__device__ __forceinline__ int xcd_swz(int bid, int nwg) {
    const int q = nwg >> 3, r = nwg & 7;
    const int xcd = bid & 7, o = bid >> 3;
    const int base = (xcd < r) ? xcd * (q + 1) : r * (q + 1) + (xcd - r) * q;
    return base + o;
}

// async global->LDS, 16B per lane. LDS dest = wave-uniform base + lane*16.
__device__ __forceinline__ void load16(const bf16_t* g, bf16_t* l) {
    __builtin_amdgcn_global_load_lds(
        (const __attribute__((address_space(1))) unsigned int*)g,
        (__attribute__((address_space(3))) unsigned int*)l, 16, 0, 0);
}

#define SBAR asm volatile("s_barrier" ::: "memory")
#define SCH  __builtin_amdgcn_sched_barrier(0)
#define PRIO1 __builtin_amdgcn_s_setprio(1)
#define PRIO0 __builtin_amdgcn_s_setprio(0)
#define VMC0 asm volatile("s_waitcnt vmcnt(0)" ::: "memory")

// A-fragment prefetch: 4 frags (one m-half, one k-sub) from base+H
#define RDA(dst, base, H) do { \
    _Pragma("unroll") \
    for (int i_ = 0; i_ < 4; ++i_) \
        dst[i_] = *(const bf16x8*)((base) + (H) + i_ * 1024); \
} while (0)
// B-fragment prefetch: 4 frags (both n-halves, one k-sub)
#define RDB(dst, base) do { \
    dst[0] = *(const bf16x8*)(base); \
    dst[1] = *(const bf16x8*)((base) + 1024); \
    dst[2] = *(const bf16x8*)((base) + 8192); \
    dst[3] = *(const bf16x8*)((base) + 8192 + 1024); \
} while (0)
// 16-MFMA cluster: one m-half x all 4 n-frags x one k-sub
#define CL16(mh, A_, B_) do { \
    _Pragma("unroll") \
    for (int mi = 0; mi < 4; ++mi) \
    _Pragma("unroll") \
    for (int nj = 0; nj < 4; ++nj) \
        acc[(mh) * 4 + mi][nj] = __builtin_amdgcn_mfma_f32_16x16x32_bf16( \
            A_[mi], B_[nj], acc[(mh) * 4 + mi][nj], 0, 0, 0); \
} while (0)
// phase scheduling pin: nr ds_reads then 16 MFMAs (LLVM SchedGroupMask:
// DS_READ=0x100, MFMA=0x8); stage VMEM + VALU float freely in the region.
#define PH(nr) do { \
    __builtin_amdgcn_sched_group_barrier(0x100, nr, 0); \
    __builtin_amdgcn_sched_group_barrier(0x008, 16, 0); \
    SCH; \
} while (0)

// 256x256 tile, BK=64, 8 waves. LDS layout (elems): [buf:32768][op:16384]
// [half:8192][row:64] with 16B slot swizzle slot ^= (row&7). K mult of 128.
// Per-tile phases (mh,ks): phi1(0,0) phi2(0,1) phi3(1,0) phi4(1,1); each
// phase prefetches the NEXT phase's fragments; phi4 starts the next tile's.
// Barrier+vmcnt(0) at phi4 head: certifies next buf's stage (loads 3-4
// phases old) AND that all waves finished this buf's reads (last at phi3).
__device__ __forceinline__ void mm8_core(
    const bf16_t* Ag, const bf16_t* Bg, int lda, int ldb, int K,
    bf16_t* lds, int w, int l, f32x4 acc[8][4])
{
    const long ldal = lda, ldbl = ldb;
    const int fr = l & 15, kq = l >> 4;
    // staging geometry: lane l -> row rr, 16B slot (l&7), logical slot (l&7)^(rr&7)
    const int rr = w * 8 + (l >> 3);
    const int c8e = ((l & 7) ^ (l >> 3)) * 8;
    const bf16_t* pA[2];
    const bf16_t* pB[2];
    pA[0] = Ag + (long)rr * ldal + c8e;
    pA[1] = pA[0] + 128 * ldal;
    pB[0] = Bg + (long)rr * ldbl + c8e;
    pB[1] = pB[0] + 128 * ldbl;
    // ds_read swizzled slot offsets for k-sub 0/1
    const int s0 = ((0 + kq) ^ (fr & 7)) * 8;
    const int s1 = ((4 + kq) ^ (fr & 7)) * 8;
    const int arow = ((w >> 2) * 64 + fr) * 64;
    const int brow = ((w & 3) * 32 + fr) * 64;
    // read bases: A/B x buf x k-sub (H imm selects m-half / n-half)
    const bf16_t* A00 = lds + arow + s0;
    const bf16_t* A01 = lds + arow + s1;
    const bf16_t* A10 = lds + 32768 + arow + s0;
    const bf16_t* A11 = lds + 32768 + arow + s1;
    const bf16_t* B00 = lds + 16384 + brow + s0;
    const bf16_t* B01 = lds + 16384 + brow + s1;
    const bf16_t* B10 = lds + 49152 + brow + s0;
    const bf16_t* B11 = lds + 49152 + brow + s1;
    bf16_t* stA = lds + w * 512;
    bf16_t* stB = lds + 16384 + w * 512;

    auto stg = [&](int b, int isB, int h, int t) {
        const bf16_t* g = (isB ? pB[h] : pA[h]) + (long)t * 64;
        bf16_t* d = (isB ? stB : stA) + b * 32768 + h * 8192;
        load16(g, d);
        load16(g + 64 * (isB ? ldbl : ldal), d + 4096);
    };

    bf16x8 a0[4], a1[4], b0[4], b1[4];
    const int NT = K >> 6, NI = NT >> 1;

    // prologue: stage t0 fully + t1 top halves; certify t0; prime phi1(t0).
    stg(0, 0, 0, 0); stg(0, 1, 0, 0); stg(0, 0, 1, 0); stg(0, 1, 1, 0);
    stg(1, 0, 0, 1); stg(1, 1, 0, 1);
    asm volatile("s_waitcnt vmcnt(4)" ::: "memory");
    SBAR; SCH;
    RDA(a0, A00, 0); RDB(b0, B00);
    SCH;

    for (int i = 0; i < NI; ++i) {
        const int tn1 = 2 * i + 1;
        int tn2 = 2 * i + 2; if (tn2 >= NT) tn2 -= 2;  // tail: clamp, unused
        int tn3 = 2 * i + 3; if (tn3 >= NT) tn3 -= 2;
        // ---- even tile (buf0) ----
        // phi1: MFMA(m0,k0); pf (m0,k1); stage Ab,Bb(t+1 -> buf1)
        RDA(a1, A01, 0); RDB(b1, B01);
        stg(1, 0, 1, tn1); stg(1, 1, 1, tn1);
        PRIO1; CL16(0, a0, b0); PRIO0;
        PH(8);
        // phi2: MFMA(m0,k1); pf (m1,k0)
        RDA(a0, A00, 8192);
        PRIO1; CL16(0, a1, b1); PRIO0;
        PH(4);
        // phi3: MFMA(m1,k0); pf (m1,k1)  [last buf0 reads this tile]
        RDA(a1, A01, 8192);
        PRIO1; CL16(1, a0, b0); PRIO0;
        PH(4);
        // phi4: certify buf1 stage + buf0 reads done; stage At,Bt(t+2 -> buf0);
        //       pf (m0,k0) of odd tile from buf1; MFMA(m1,k1)
        VMC0;
        SBAR; SCH;
        stg(0, 0, 0, tn2); stg(0, 1, 0, tn2);
        RDA(a0, A10, 0); RDB(b0, B10);
        PRIO1; CL16(1, a1, b1); PRIO0;
        PH(8);
        // ---- odd tile (buf1) ----
        // phi1: MFMA(m0,k0); pf (m0,k1); stage Ab,Bb(t+2 -> buf0)
        RDA(a1, A11, 0); RDB(b1, B11);
        stg(0, 0, 1, tn2); stg(0, 1, 1, tn2);
        PRIO1; CL16(0, a0, b0); PRIO0;
        PH(8);
        // phi2: MFMA(m0,k1); pf (m1,k0)
        RDA(a0, A10, 8192);
        PRIO1; CL16(0, a1, b1); PRIO0;
        PH(4);
        // phi3: MFMA(m1,k0); pf (m1,k1)
        RDA(a1, A11, 8192);
        PRIO1; CL16(1, a0, b0); PRIO0;
        PH(4);
        // phi4: certify buf0 stage (t+2) + buf1 reads done; stage At,Bt(t+3
        //       -> buf1); pf (m0,k0) of next even tile from buf0; MFMA(m1,k1)
        VMC0;
        SBAR; SCH;
        stg(1, 0, 0, tn3); stg(1, 1, 0, tn3);
        RDA(a0, A00, 0); RDB(b0, B00);
        PRIO1; CL16(1, a1, b1); PRIO0;
        PH(8);
    }
    // drain garbage tail staging before LDS reuse (epilogue)
    VMC0;
    SBAR; SCH;
}

// Standard GEMM: C[M,N] = scale*A@B^T + bias, opt ReLU, bf16 out.
// CLAMPK: K clamped to (by+1)*256 - koff (causal PV); zero tile if <=0.
// dsc.trans: write transposed into vtb layout [batch][N][2048].
template <bool RELU, bool CLAMPK>
__global__ __launch_bounds__(512, 2) void mm8_std(
    MMArgs args, int M, int N, int K, int lda, int ldb, float scale, int GX)
{
    __shared__ __align__(16) bf16_t lds[65536];  // 128 KiB
    const MMDesc dsc = args.g[blockIdx.z];

    const int lin = xcd_swz(blockIdx.x, gridDim.x);
    const int panel = lin / (8 * GX);
    const int rem = lin - panel * 8 * GX;
    const int bx = rem >> 3;
    const int by = panel * 8 + (rem & 7);
    const int m0 = by * 256, n0 = bx * 256;
    const int tid = threadIdx.x, w = tid >> 6, l = tid & 63;

    f32x4 acc[8][4];
    const f32x4 z4 = {0.f, 0.f, 0.f, 0.f};
#pragma unroll
    for (int i = 0; i < 8; ++i)
#pragma unroll
        for (int j = 0; j < 4; ++j) acc[i][j] = z4;

    int Keff = K;
    if (CLAMPK) {
        int km = (by + 1) * 256 - dsc.koff;
        Keff = km < K ? km : K;
    }
    if (!CLAMPK || Keff > 0)
        mm8_core(dsc.A + (long)m0 * lda, dsc.B + (long)n0 * ldb,
                 lda, ldb, Keff, lds, w, l, acc);

    // epilogue: bias/scale/relu -> LDS stage (two 128-row halves) -> coalesced out
    const int fr = l & 15, erow = (l >> 4) * 4;
    const int wrow = (w >> 2) * 64, wcol = (w & 3) * 32;
    bf16_t* ctb = lds;
    __hip_bfloat16* ct = (__hip_bfloat16*)lds;
#pragma unroll
    for (int mh = 0; mh < 2; ++mh) {
        if (mh) __syncthreads();
#pragma unroll
        for (int nh = 0; nh < 2; ++nh)
#pragma unroll
            for (int ni = 0; ni < 2; ++ni) {
                const int cl = nh * 128 + wcol + ni * 16 + fr;
                const float bv = dsc.bias ? dsc.bias[n0 + cl] : 0.f;
#pragma unroll
                for (int mi = 0; mi < 4; ++mi) {
                    const int lr = wrow + mi * 16 + erow;
                    const f32x4 a = acc[mh * 4 + mi][nh * 2 + ni];
                    if (dsc.trans) {
                        bf16x4 p;
#pragma unroll
                        for (int r = 0; r < 4; ++r) {
                            float v = a[r] * scale + bv;
                            if (RELU) v = fmaxf(v, 0.f);
                            p[r] = (bf16_t)v;
                        }
                        *(bf16x4*)(ctb + cl * 140 + lr) = p;
                    } else {
#pragma unroll
                        for (int r = 0; r < 4; ++r) {
                            float v = a[r] * scale + bv;
                            if (RELU) v = fmaxf(v, 0.f);
                            ct[(lr + r) * 264 + cl] = __float2bfloat16(v);
                        }
                    }
                }
            }
        __syncthreads();
        if (dsc.trans) {  // V projection -> vtb[batch][e][s]
            __hip_bfloat16* base = dsc.C + ((long)(m0 >> 11) * N + n0) * 2048
                                 + (m0 & 2047) + mh * 128;
#pragma unroll
            for (int u = 0; u < 8; ++u) {
                const int e = u * 4096 + tid * 8;
                const int rl = e >> 7, cl = e & 127;
                const bf16_t* src = ctb + rl * 140 + cl;
                const uint2 lo = *(const uint2*)(src);
                const uint2 hi = *(const uint2*)(src + 4);
                const uint4 v = {lo.x, lo.y, hi.x, hi.y};
                *(uint4*)(base + (long)rl * 2048 + cl) = v;
            }
        } else {
            __hip_bfloat16* base = dsc.C + (long)(m0 + mh * 128) * N + n0;
#pragma unroll
            for (int u = 0; u < 8; ++u) {
                const int e = u * 4096 + tid * 8;
                *(uint4*)(base + (long)(e >> 8) * N + (e & 255))
                    = *(const uint4*)(ct + (e >> 8) * 264 + (e & 255));
            }
        }
    }
}

// QK^T with fused exp epilogue: P~ = exp(scale*(A@B^T)) bf16, row sums -> lsum.
template <bool CAUSAL>
__global__ __launch_bounds__(512, 2) void mm8_exp(
    MMArgs args, int N, int K, int lda, int ldb, float scale, int GX)
{
    __shared__ __align__(16) bf16_t lds[65536];
    const MMDesc dsc = args.g[blockIdx.z];

    int bx, by;
    if (CAUSAL) {
        const int t = xcd_swz(blockIdx.x, gridDim.x);
        by = (int)((sqrtf(8.f * t + 1.f) - 1.f) * 0.5f);
        while ((by + 1) * (by + 2) / 2 <= t) ++by;
        while (by * (by + 1) / 2 > t) --by;
        bx = t - by * (by + 1) / 2;
    } else {
        const int lin = xcd_swz(blockIdx.x, gridDim.x);
        const int panel = lin / (8 * GX);
        const int rem = lin - panel * 8 * GX;
        bx = rem >> 3;
        by = panel * 8 + (rem & 7);
    }
    const int m0 = by * 256, n0 = bx * 256;
    const int tid = threadIdx.x, w = tid >> 6, l = tid & 63;

    f32x4 acc[8][4];
    const f32x4 z4 = {0.f, 0.f, 0.f, 0.f};
#pragma unroll
    for (int i = 0; i < 8; ++i)
#pragma unroll
        for (int j = 0; j < 4; ++j) acc[i][j] = z4;

    mm8_core(dsc.A + (long)m0 * lda, dsc.B + (long)n0 * ldb,
             lda, ldb, K, lds, w, l, acc);

    const int fr = l & 15, erow = (l >> 4) * 4;
    const int wrow = (w >> 2) * 64, wcol = (w & 3) * 32;
    __hip_bfloat16* ct = (__hip_bfloat16*)lds;
#pragma unroll
    for (int mh = 0; mh < 2; ++mh) {
        if (mh) __syncthreads();
#pragma unroll
        for (int mi = 0; mi < 4; ++mi) {
            const int lr = wrow + mi * 16 + erow;
#pragma unroll
            for (int r = 0; r < 4; ++r) {
                const int grow = m0 + mh * 128 + lr + r;
                float rs = 0.f;
#pragma unroll
                for (int nh = 0; nh < 2; ++nh)
#pragma unroll
                    for (int ni = 0; ni < 2; ++ni) {
                        const int cl = nh * 128 + wcol + ni * 16 + fr;
                        float e;
                        if (CAUSAL && (n0 + cl) > grow)
                            e = 0.f;
                        else
                            e = __expf(acc[mh * 4 + mi][nh * 2 + ni][r] * scale);
                        ct[(lr + r) * 264 + cl] = __float2bfloat16(e);
                        rs += e;
                    }
#pragma unroll
                for (int o = 8; o > 0; o >>= 1) rs += __shfl_down(rs, o, 16);
                if ((l & 15) == 0) atomicAdd(&dsc.lsum[grow], rs);
            }
        }
        __syncthreads();
        __hip_bfloat16* base = dsc.C + (long)(m0 + mh * 128) * N + n0;
#pragma unroll
        for (int u = 0; u < 8; ++u) {
            const int e = u * 4096 + tid * 8;
            *(uint4*)(base + (long)(e >> 8) * N + (e & 255))
                = *(const uint4*)(ct + (e >> 8) * 264 + (e & 255));
        }
    }
}

// ---------------- reductions ----------------
__device__ __forceinline__ float waveReduceSum(float v) {
#pragma unroll
    for (int o = 32; o > 0; o >>= 1) v += __shfl_down(v, o, 64);
    return v;
}
__device__ __forceinline__ float blockReduceSum(float v, float* s) {
    int lane = threadIdx.x & 63, w = threadIdx.x >> 6;
    v = waveReduceSum(v);
    __syncthreads();
    if (lane == 0) s[w] = v;
    __syncthreads();
    return s[0] + s[1] + s[2] + s[3];
}

// out = LayerNorm(xbase + t) * g + beta.  h1,h2 bf16 partials.
template <bool BR, bool XF32>
__global__ __launch_bounds__(256) void ln_kernel(
    const float* __restrict__ xf, const __hip_bfloat16* __restrict__ xh,
    const __hip_bfloat16* __restrict__ h1, const __hip_bfloat16* __restrict__ h2,
    const float* __restrict__ hbias, const float* __restrict__ lsum,
    const float* __restrict__ g, const float* __restrict__ beta,
    float* __restrict__ outf, __hip_bfloat16* __restrict__ outb) {
    __shared__ float red[4];
    const int E = 768;
    const long row = blockIdx.x;
    const float hscale = lsum ? (1.f / lsum[row]) : 1.f;

    float vals[3];
    float sum = 0.f;
#pragma unroll
    for (int i = 0; i < 3; ++i) {
        int c = threadIdx.x + i * 256;
        float t = __bfloat162float(h1[row * E + c]) + __bfloat162float(h2[row * E + c]);
        if (BR) t = fmaxf(t + hbias[c], 0.f);
        else t *= hscale;
        float xv = XF32 ? xf[row * E + c] : __bfloat162float(xh[row * E + c]);
        vals[i] = xv + t;
        sum += vals[i];
    }
    sum = blockReduceSum(sum, red);
    const float mean = sum * (1.f / 768.f);

    float ss = 0.f;
#pragma unroll
    for (int i = 0; i < 3; ++i) {
        float d = vals[i] - mean;
        ss += d * d;
    }
    ss = blockReduceSum(ss, red);
    const float inv = rsqrtf(ss * (1.f / 768.f) + 1e-5f);

#pragma unroll
    for (int i = 0; i < 3; ++i) {
        int c = threadIdx.x + i * 256;
        float v = (vals[i] - mean) * inv * g[c] + beta[c];
        if (outf) outf[row * E + c] = v;
        if (outb) outb[row * E + c] = __float2bfloat16(v);
    }
}

// one launch converts all fp32->bf16 (8 weights + x + kv) and zeroes lsum.
struct CvtPtrs {
    const float* s[10];
    __hip_bfloat16* d[10];
    float* zero;  // 2*Nr floats to zero
};
__global__ __launch_bounds__(256) void cvt_all(CvtPtrs p) {
    int bid = blockIdx.x, seg, off;
    if (bid >= 20352) {  // zero lsum1+lsum2: 16 blocks x 256 x 4 floats
        int i = (bid - 20352) * 1024 + threadIdx.x * 4;
        float4 z = {0.f, 0.f, 0.f, 0.f};
        *(float4*)(p.zero + i) = z;
        return;
    }
    if (bid < 3456) {
        seg = bid / 576;
        off = (bid % 576) * 1024;
    } else if (bid < 8064) {
        int t = bid - 3456;
        seg = 6 + t / 2304;
        off = (t % 2304) * 1024;
    } else {
        int t = bid - 8064;
        seg = 8 + t / 6144;
        off = (t % 6144) * 1024;
    }
    const float* s = p.s[seg];
    __hip_bfloat16* d = p.d[seg];
    int i = off + threadIdx.x * 4;
    float4 v = *(const float4*)(s + i);
    d[i + 0] = __float2bfloat16(v.x);
    d[i + 1] = __float2bfloat16(v.y);
    d[i + 2] = __float2bfloat16(v.z);
    d[i + 3] = __float2bfloat16(v.w);
}

extern "C" void kernel_launch(void* const* d_in, const int* in_sizes, int n_in,
                              void* d_out, int out_size, void* d_ws, size_t ws_size,
                              hipStream_t stream) {
    const int Bb = 4, S = 2048, E = 768, DFF = 3072;
    const int Nr = Bb * S;  // 8192

    const float* x    = (const float*)d_in[0];
    const float* kv   = (const float*)d_in[1];
    const float* wq_w = (const float*)d_in[2];
    const float* wq_b = (const float*)d_in[3];
    const float* wk_w = (const float*)d_in[4];
    const float* wk_b = (const float*)d_in[5];
    const float* wv_w = (const float*)d_in[6];
    const float* wv_b = (const float*)d_in[7];
    const float* ln1g = (const float*)d_in[8];
    const float* ln1b = (const float*)d_in[9];
    const float* wq2w = (const float*)d_in[10];
    const float* wq2b = (const float*)d_in[11];
    const float* wk2w = (const float*)d_in[12];
    const float* wk2b = (const float*)d_in[13];
    const float* wv2w = (const float*)d_in[14];
    const float* wv2b = (const float*)d_in[15];
    const float* ln2g = (const float*)d_in[16];
    const float* ln2b = (const float*)d_in[17];
    const float* w1   = (const float*)d_in[18];
    const float* b1   = (const float*)d_in[19];
    const float* w2   = (const float*)d_in[20];
    const float* b2   = (const float*)d_in[21];
    const float* ln3g = (const float*)d_in[22];
    const float* ln3b = (const float*)d_in[23];
    float* out = (float*)d_out;

    // ---- workspace (bump allocator, 256B aligned) ~155 MB ----
    char* wsp = (char*)d_ws;
    auto alloc = [&](size_t bytes) {
        char* p = wsp;
        wsp += (bytes + 255) & ~(size_t)255;
        return p;
    };
    const size_t nSE = (size_t)Nr * E;       // 6,291,456
    const size_t nSS = (size_t)Bb * S * S;   // 16,777,216
    __hip_bfloat16* Pb   = (__hip_bfloat16*)alloc(nSS * 2);   // 33.5 MB
    __hip_bfloat16* qb   = (__hip_bfloat16*)alloc(nSE * 2);
    __hip_bfloat16* kb   = (__hip_bfloat16*)alloc(nSE * 2);
    __hip_bfloat16* hffb = Pb;  // MLP hidden overlays Pb+qb+kb (58.7 >= 50.3 MB)
    __hip_bfloat16* vtb  = (__hip_bfloat16*)alloc(nSE * 2);   // V^T [b][E][S]
    __hip_bfloat16* xb   = (__hip_bfloat16*)alloc(nSE * 2);
    __hip_bfloat16* kvb  = (__hip_bfloat16*)alloc(nSE * 2);
    __hip_bfloat16* actb = (__hip_bfloat16*)alloc(nSE * 2);   // residual chain
    __hip_bfloat16* hA   = (__hip_bfloat16*)alloc(nSE * 2);   // split-K partial A
    __hip_bfloat16* hB   = (__hip_bfloat16*)alloc(nSE * 2);   // split-K partial B
    __hip_bfloat16* wqb   = (__hip_bfloat16*)alloc((size_t)E * E * 2);
    __hip_bfloat16* wkb   = (__hip_bfloat16*)alloc((size_t)E * E * 2);
    __hip_bfloat16* wvb   = (__hip_bfloat16*)alloc((size_t)E * E * 2);
    __hip_bfloat16* wq2bm = (__hip_bfloat16*)alloc((size_t)E * E * 2);
    __hip_bfloat16* wk2bm = (__hip_bfloat16*)alloc((size_t)E * E * 2);
    __hip_bfloat16* wv2bm = (__hip_bfloat16*)alloc((size_t)E * E * 2);
    __hip_bfloat16* w1b   = (__hip_bfloat16*)alloc((size_t)DFF * E * 2);
    __hip_bfloat16* w2b   = (__hip_bfloat16*)alloc((size_t)E * DFF * 2);
    float* lsum1 = (float*)alloc((size_t)Nr * 4);
    float* lsum2 = (float*)alloc((size_t)Nr * 4);

    // K2 / V2^T live in d_out used as scratch (exactly 2*nSE*2 bytes = out_size);
    // both are dead before ln3 writes the real output.
    __hip_bfloat16* k2b  = (__hip_bfloat16*)d_out;
    __hip_bfloat16* vtb2 = k2b + nSE;

    const float scale = 1.0f / sqrtf((float)E);
    const dim3 blk(256);
    const dim3 blk5(512);

    // ---- all conversions + lsum zeroing in one launch ----
    CvtPtrs cp;
    cp.s[0] = wq_w; cp.d[0] = wqb;
    cp.s[1] = wk_w; cp.d[1] = wkb;
    cp.s[2] = wv_w; cp.d[2] = wvb;
    cp.s[3] = wq2w; cp.d[3] = wq2bm;
    cp.s[4] = wk2w; cp.d[4] = wk2bm;
    cp.s[5] = wv2w; cp.d[5] = wv2bm;
    cp.s[6] = w1;   cp.d[6] = w1b;
    cp.s[7] = w2;   cp.d[7] = w2b;
    cp.s[8] = x;    cp.d[8] = xb;
    cp.s[9] = kv;   cp.d[9] = kvb;
    cp.zero = lsum1;  // lsum1+lsum2 contiguous (2*Nr floats)
    cvt_all<<<8064 + 12288 + 16, blk, 0, stream>>>(cp);

    // ---- fused projections: Q,K,V(self from xb) + K2,V2(cross from kvb) ----
    {   // 5 z-slices x 96 blocks = 480 blocks
        MMArgs a{};
        a.g[0] = {(const bf16_t*)xb,  (const bf16_t*)wqb,   wq_b, qb,   nullptr, 0, 0};
        a.g[1] = {(const bf16_t*)xb,  (const bf16_t*)wkb,   wk_b, kb,   nullptr, 0, 0};
        a.g[2] = {(const bf16_t*)xb,  (const bf16_t*)wvb,   wv_b, vtb,  nullptr, 0, 1};
        a.g[3] = {(const bf16_t*)kvb, (const bf16_t*)wk2bm, wk2b, k2b,  nullptr, 0, 0};
        a.g[4] = {(const bf16_t*)kvb, (const bf16_t*)wv2bm, wv2b, vtb2, nullptr, 0, 1};
        mm8_std<false, false><<<dim3(96, 1, 5), blk5, 0, stream>>>(
            a, Nr, E, E, E, E, 1.f, 3);
    }
    // ---- causal self-attention ----
    {   // causal QK^T + exp: 36 triangle tiles x 4 batches
        MMArgs a{};
        for (int b = 0; b < 4; ++b)
            a.g[b] = {(const bf16_t*)qb + (long)b * S * E,
                      (const bf16_t*)kb + (long)b * S * E, nullptr,
                      Pb + (long)b * S * S, lsum1 + b * S, 0, 0};
        mm8_exp<true><<<dim3(36, 1, 4), blk5, 0, stream>>>(a, S, E, E, E, scale, 8);
    }
    {   // causal PV split-K=2 with K-clamp, bf16 partials
        MMArgs a{};
        for (int b = 0; b < 4; ++b)
            for (int ks = 0; ks < 2; ++ks)
                a.g[b * 2 + ks] = {(const bf16_t*)Pb + (long)b * S * S + ks * 1024,
                                   (const bf16_t*)vtb + (long)b * E * S + ks * 1024,
                                   nullptr, (ks ? hB : hA) + (long)b * S * E,
                                   nullptr, ks * 1024, 0};
        mm8_std<false, true><<<dim3(24, 1, 8), blk5, 0, stream>>>(
            a, S, E, 1024, S, S, 1.f, 3);
    }
    ln_kernel<false, false><<<Nr, blk, 0, stream>>>(
        nullptr, xb, hA, hB, nullptr, lsum1, ln1g, ln1b, nullptr, actb);

    // ---- cross-attention ----
    {   // Q2 projection only (K2/V2 already done)
        MMArgs a{};
        a.g[0] = {(const bf16_t*)actb, (const bf16_t*)wq2bm, wq2b, qb, nullptr, 0, 0};
        mm8_std<false, false><<<dim3(96, 1, 1), blk5, 0, stream>>>(
            a, Nr, E, E, E, E, 1.f, 3);
    }
    {   // full QK^T + exp: 64 tiles x 4 batches
        MMArgs a{};
        for (int b = 0; b < 4; ++b)
            a.g[b] = {(const bf16_t*)qb + (long)b * S * E,
                      (const bf16_t*)k2b + (long)b * S * E, nullptr,
                      Pb + (long)b * S * S, lsum2 + b * S, 0, 0};
        mm8_exp<false><<<dim3(64, 1, 4), blk5, 0, stream>>>(a, S, E, E, E, scale, 8);
    }
    {   // full PV split-K=2, bf16 partials
        MMArgs a{};
        for (int b = 0; b < 4; ++b)
            for (int ks = 0; ks < 2; ++ks)
                a.g[b * 2 + ks] = {(const bf16_t*)Pb + (long)b * S * S + ks * 1024,
                                   (const bf16_t*)vtb2 + (long)b * E * S + ks * 1024,
                                   nullptr, (ks ? hB : hA) + (long)b * S * E,
                                   nullptr, 0, 0};
        mm8_std<false, false><<<dim3(24, 1, 8), blk5, 0, stream>>>(
            a, S, E, 1024, S, S, 1.f, 3);
    }
    ln_kernel<false, false><<<Nr, blk, 0, stream>>>(
        nullptr, actb, hA, hB, nullptr, lsum2, ln2g, ln2b, nullptr, actb);

    // ---- MLP ----
    {   // MLP1: fused bias+ReLU (hffb overlays Pb/qb/kb)
        MMArgs a{};
        a.g[0] = {(const bf16_t*)actb, (const bf16_t*)w1b, b1, hffb, nullptr, 0, 0};
        mm8_std<true, false><<<dim3(384, 1, 1), blk5, 0, stream>>>(
            a, Nr, DFF, E, E, E, 1.f, 12);
    }
    {   // MLP2 split-K=2, bf16 partials; bias+ReLU applied in ln3
        MMArgs a{};
        a.g[0] = {(const bf16_t*)hffb, (const bf16_t*)w2b, nullptr, hA, nullptr, 0, 0};
        a.g[1] = {(const bf16_t*)hffb + 1536, (const bf16_t*)w2b + 1536, nullptr,
                  hB, nullptr, 0, 0};
        mm8_std<false, false><<<dim3(96, 1, 2), blk5, 0, stream>>>(
            a, Nr, E, 1536, DFF, DFF, 1.f, 3);
    }
    ln_kernel<true, false><<<Nr, blk, 0, stream>>>(
        nullptr, actb, hA, hB, b2, nullptr, ln3g, ln3b, out, nullptr);
}